// Round 12
// baseline (133.391 us; speedup 1.0000x reference)
//
#include <hip/hip_runtime.h>

#define NB      32
#define NPB     16384
#define KTOP    2048
#define NF      64
#define NBINS   4096        // 12-bit bucket = key32 >> 20
#define CANDCAP 4096
#define NCH     8           // chunks per batch
#define CROWS   2048        // rows per chunk

// Padded LDS index for the bitonic net (u64 elements).
__device__ __forceinline__ int PAD(int i) { return i + (i >> 5); }

// Monotone map: float -> uint32 such that float order == unsigned order.
__device__ __forceinline__ unsigned mono(float f) {
  unsigned u = __float_as_uint(f);
  return (u & 0x80000000u) ? ~u : (u | 0x80000000u);
}

// K1: 256 blocks x 1024 thr (one block per 2048-row chunk): extract key
// column + private per-chunk u16 histogram.
__global__ __launch_bounds__(1024) void extract_hist_kernel(const float* __restrict__ in,
                                                            unsigned* __restrict__ keybuf,
                                                            unsigned* __restrict__ subhist32) {
  __shared__ unsigned h[NBINS];                  // 16 KiB
  const int g = blockIdx.x, tid = threadIdx.x;
  for (int i = tid; i < NBINS; i += 1024) h[i] = 0;
  __syncthreads();
  const int row0 = g * CROWS;
  unsigned k0 = mono(in[(size_t)(row0 + tid) * NF]);
  unsigned k1 = mono(in[(size_t)(row0 + tid + 1024) * NF]);
  keybuf[row0 + tid] = k0;
  keybuf[row0 + tid + 1024] = k1;
  atomicAdd(&h[k0 >> 20], 1u);
  atomicAdd(&h[k1 >> 20], 1u);
  __syncthreads();
  unsigned* out = subhist32 + (size_t)g * (NBINS / 2);
  for (int i = tid; i < NBINS / 2; i += 1024)
    out[i] = h[2 * i] | (h[2 * i + 1] << 16);    // counts <= 2048, fit u16
}

// K23: 256 blocks (one per chunk), 512 threads, 8 bins/thread. Each block
// redundantly computes its batch's suffix-scan from the 8 sub-hists (L2-hot),
// derives floor bin D / Ncand / its own chunk's per-bin start offsets, then
// bucket-places its chunk's winners. cch==0 blocks also write aboveg+finfo.
// *** R12: launched 4x as a DECOMPOSITION MEASUREMENT (idempotent). ***
__global__ __launch_bounds__(512) void scan_compact_kernel(const unsigned* __restrict__ keybuf,
                                                           const unsigned short* __restrict__ subhist,
                                                           unsigned* __restrict__ aboveg,
                                                           uint2* __restrict__ finfo,
                                                           unsigned long long* __restrict__ cand) {
  __shared__ unsigned ofs[NBINS];                // 16 KiB
  __shared__ unsigned wtot[8], wsfx[8];
  __shared__ unsigned sh_D;
  const int g = blockIdx.x, tid = threadIdx.x;
  const int b = g >> 3, cch = g & 7;
  const int wid = tid >> 6, lane = tid & 63;

  // Per-chunk counts for my 8 bins [8*tid, 8*tid+8) across the 8 chunks.
  unsigned short cnt[NCH][8];
  unsigned tot[8];
#pragma unroll
  for (int j = 0; j < 8; ++j) tot[j] = 0;
#pragma unroll
  for (int c = 0; c < NCH; ++c) {
    const uint4 v = *(const uint4*)(subhist + (size_t)(b * NCH + c) * NBINS + 8 * tid);
    cnt[c][0] = (unsigned short)(v.x & 0xffff); cnt[c][1] = (unsigned short)(v.x >> 16);
    cnt[c][2] = (unsigned short)(v.y & 0xffff); cnt[c][3] = (unsigned short)(v.y >> 16);
    cnt[c][4] = (unsigned short)(v.z & 0xffff); cnt[c][5] = (unsigned short)(v.z >> 16);
    cnt[c][6] = (unsigned short)(v.w & 0xffff); cnt[c][7] = (unsigned short)(v.w >> 16);
#pragma unroll
    for (int j = 0; j < 8; ++j) tot[j] += cnt[c][j];
  }
  unsigned s = 0;
#pragma unroll
  for (int j = 0; j < 8; ++j) s += tot[j];

  unsigned p = s;                                // inclusive suffix over lanes
  for (int off = 1; off < 64; off <<= 1) {
    unsigned t = __shfl_down(p, off);
    if (lane + off < 64) p += t;
  }
  if (lane == 0) wtot[wid] = p;
  __syncthreads();
  if (wid == 0) {
    unsigned own = (lane < 8) ? wtot[lane] : 0;
    unsigned p2 = own;
    for (int off = 1; off < 8; off <<= 1) {
      unsigned t = __shfl_down(p2, off);
      if (lane + off < 8) p2 += t;
    }
    if (lane < 8) wsfx[lane] = p2 - own;         // totals of waves above
  }
  __syncthreads();

  unsigned run = wsfx[wid] + (p - s);            // keys strictly above my bins
  unsigned ab[8];
#pragma unroll
  for (int j = 7; j >= 0; --j) {
    ab[j] = run;                                 // above[bin 8*tid+j]
    run += tot[j];
    if (ab[j] < KTOP && run >= KTOP) {           // exactly one bin satisfies
      sh_D = (unsigned)(8 * tid + j);
      if (cch == 0) {
        unsigned N = run < CANDCAP ? run : CANDCAP;
        finfo[b] = make_uint2((unsigned)(8 * tid + j), N);
      }
    }
  }
  if (cch == 0) {
    uint4* abo = (uint4*)(aboveg + (size_t)b * NBINS + 8 * tid);
    abo[0] = make_uint4(ab[0], ab[1], ab[2], ab[3]);
    abo[1] = make_uint4(ab[4], ab[5], ab[6], ab[7]);
  }

  // My chunk's start offsets: above[bin] + sum over earlier chunks' counts.
  unsigned st[8];
#pragma unroll
  for (int j = 0; j < 8; ++j) st[j] = ab[j];
  for (int c = 0; c < NCH; ++c) {
    if (c < cch) {
#pragma unroll
      for (int j = 0; j < 8; ++j) st[j] += cnt[c][j];
    }
  }
#pragma unroll
  for (int j = 0; j < 8; ++j) ofs[8 * tid + j] = st[j];
  __syncthreads();

  // Compact this chunk's winners to their bucket-sorted slots.
  const unsigned D = sh_D;
  const int row0 = g * CROWS;
  unsigned long long* cb = cand + (size_t)b * CANDCAP;
#pragma unroll
  for (int j = 0; j < CROWS / 512; ++j) {
    int row = row0 + tid + j * 512;
    unsigned k = keybuf[row];
    unsigned bin = k >> 20;
    if (bin >= D) {
      unsigned slot = atomicAdd(&ofs[bin], 1u);
      if (slot < CANDCAP) {
        unsigned li = (unsigned)(row & (NPB - 1));
        cb[slot] = ((unsigned long long)k << 32) | (unsigned)~li;
      }
    }
  }
}

// K4: 256 blocks (8/batch): sort one bin-aligned chunk [E1,E2) of the
// candidate array in LDS, then gather output rows [E1, min(E2,KTOP)) directly.
// *** R12: launched 4x as a DECOMPOSITION MEASUREMENT (idempotent). ***
__global__ __launch_bounds__(512) void sort_gather_kernel(const float* __restrict__ in,
                                                          const unsigned* __restrict__ aboveg,
                                                          const uint2* __restrict__ finfo,
                                                          const unsigned long long* __restrict__ cand,
                                                          float* __restrict__ out) {
  __shared__ unsigned long long sb[1024 + 32];   // padded bitonic buffer
  __shared__ unsigned shE[2];
  const int g = blockIdx.x, tid = threadIdx.x;
  const int b = g >> 3, cch = g & 7;
  const int lane = tid & 63;

  const unsigned N = finfo[b].y;                 // KTOP <= N <= CANDCAP
  const unsigned x1 = (unsigned)cch * 512u, x2 = x1 + 512u;
  if (x1 >= KTOP) return;                        // chunk entirely past rank KTOP

  if (tid < 2) shE[tid] = 0xffffffffu;
  __syncthreads();
  // E(x) = min{ above[bin] : above[bin] >= x }; N itself is a bin boundary.
  unsigned m1 = 0xffffffffu, m2 = 0xffffffffu;
  const uint4* ab4 = (const uint4*)(aboveg + (size_t)b * NBINS);
  for (int i = tid; i < NBINS / 4; i += 512) {
    uint4 v = ab4[i];
#pragma unroll
    for (int q = 0; q < 4; ++q) {
      unsigned a = (&v.x)[q];
      if (a >= x1 && a < m1) m1 = a;
      if (a >= x2 && a < m2) m2 = a;
    }
  }
  for (int off = 1; off < 64; off <<= 1) {
    unsigned t1 = __shfl_xor(m1, off), t2 = __shfl_xor(m2, off);
    m1 = m1 < t1 ? m1 : t1;
    m2 = m2 < t2 ? m2 : t2;
  }
  if (lane == 0) { atomicMin(&shE[0], m1); atomicMin(&shE[1], m2); }
  __syncthreads();

  const unsigned E1 = shE[0];
  unsigned E2 = (x2 >= N) ? N : shE[1];
  if (E2 > N) E2 = N;                            // safety
  if (E1 >= KTOP) return;                        // nothing to output from here
  int len = (int)(E2 - E1);
  if (len <= 0) return;
  if (len > 1024) len = 1024;                    // safety (cannot trigger here)

  const unsigned long long* cb = cand + (size_t)b * CANDCAP;
  for (int e = tid; e < 1024; e += 512)
    sb[PAD(e)] = (e < len) ? cb[E1 + e] : 0ULL;  // 0 sorts below any real key
  __syncthreads();

  for (int size = 2; size <= 1024; size <<= 1) {
    for (int stride = size >> 1; stride >= 1; stride >>= 1) {
      int pos = 2 * tid - (tid & (stride - 1));
      bool desc = ((pos & size) == 0);
      unsigned long long a = sb[PAD(pos)], bb = sb[PAD(pos + stride)];
      if (desc ? (a < bb) : (a > bb)) { sb[PAD(pos)] = bb; sb[PAD(pos + stride)] = a; }
      __syncthreads();
    }
  }

  // Gather output rows [E1, gend).
  const unsigned gend = (E2 < KTOP) ? E2 : KTOP;
  const int glen = (int)(gend - E1);
  const float4* inb = (const float4*)(in + (size_t)b * NPB * NF);
  float4* outb = (float4*)(out + ((size_t)b * KTOP + E1) * NF);
  for (int u = tid; u < glen * 16; u += 512) {
    int r = u >> 4, f4 = u & 15;
    unsigned long long kv = sb[PAD(r)];
    int gi = (int)(~(unsigned)(kv & 0xffffffffu));
    outb[(size_t)r * 16 + f4] = inb[(size_t)gi * 16 + f4];
  }
}

extern "C" void kernel_launch(void* const* d_in, const int* in_sizes, int n_in,
                              void* d_out, int out_size, void* d_ws, size_t ws_size,
                              hipStream_t stream) {
  const float* in = (const float*)d_in[0];
  float* out = (float*)d_out;

  // d_ws layout (MiB offsets): keybuf @0 (2), subhist u16 @2 (2),
  // aboveg @4 (0.5), cand @5 (1), finfo @6.
  unsigned* keybuf    = (unsigned*)d_ws;
  unsigned* subhist32 = (unsigned*)((char*)d_ws + (2u << 20));
  unsigned short* subhist16 = (unsigned short*)subhist32;
  unsigned* aboveg    = (unsigned*)((char*)d_ws + (4u << 20));
  unsigned long long* cand = (unsigned long long*)((char*)d_ws + (5u << 20));
  uint2* finfo        = (uint2*)((char*)d_ws + (6u << 20));

  // R12 MEASUREMENT: K23 and K4 each launched 4x (idempotent).
  // dur = base + 3*(K23 + K4 + 2*gap).
  extract_hist_kernel<<<NB * NCH, 1024, 0, stream>>>(in, keybuf, subhist32);
  scan_compact_kernel<<<NB * NCH, 512, 0, stream>>>(keybuf, subhist16, aboveg, finfo, cand);
  scan_compact_kernel<<<NB * NCH, 512, 0, stream>>>(keybuf, subhist16, aboveg, finfo, cand);
  scan_compact_kernel<<<NB * NCH, 512, 0, stream>>>(keybuf, subhist16, aboveg, finfo, cand);
  scan_compact_kernel<<<NB * NCH, 512, 0, stream>>>(keybuf, subhist16, aboveg, finfo, cand);
  sort_gather_kernel<<<NB * NCH, 512, 0, stream>>>(in, aboveg, finfo, cand, out);
  sort_gather_kernel<<<NB * NCH, 512, 0, stream>>>(in, aboveg, finfo, cand, out);
  sort_gather_kernel<<<NB * NCH, 512, 0, stream>>>(in, aboveg, finfo, cand, out);
  sort_gather_kernel<<<NB * NCH, 512, 0, stream>>>(in, aboveg, finfo, cand, out);
}

// Round 13
// 44.641 us; speedup vs baseline: 2.9881x; 2.9881x over previous
//
#include <hip/hip_runtime.h>

#define NB      32
#define NPB     16384
#define KTOP    2048
#define NF      64
#define NBINS   4096        // 12-bit bucket = key32 >> 20
#define NCH     8           // input chunks per batch (K1)
#define CROWS   2048        // rows per input chunk
#define CHSLOT  256         // candidate slots per sort chunk (8 chunks cover KTOP)
#define SCAP    1024        // sort buffer capacity

// Padded LDS index for the bitonic net (u64 elements).
__device__ __forceinline__ int PAD(int i) { return i + (i >> 5); }

// Monotone map: float -> uint32 such that float order == unsigned order.
__device__ __forceinline__ unsigned mono(float f) {
  unsigned u = __float_as_uint(f);
  return (u & 0x80000000u) ? ~u : (u | 0x80000000u);
}

// K1: 256 blocks x 1024 thr (one block per 2048-row chunk): extract key
// column + private per-chunk u16 histogram (packed u32 stores).
__global__ __launch_bounds__(1024) void extract_hist_kernel(const float* __restrict__ in,
                                                            unsigned* __restrict__ keybuf,
                                                            unsigned* __restrict__ subhist32) {
  __shared__ unsigned h[NBINS];                  // 16 KiB
  const int g = blockIdx.x, tid = threadIdx.x;
  for (int i = tid; i < NBINS; i += 1024) h[i] = 0;
  __syncthreads();
  const int row0 = g * CROWS;
  unsigned k0 = mono(in[(size_t)(row0 + tid) * NF]);
  unsigned k1 = mono(in[(size_t)(row0 + tid + 1024) * NF]);
  keybuf[row0 + tid] = k0;
  keybuf[row0 + tid + 1024] = k1;
  atomicAdd(&h[k0 >> 20], 1u);
  atomicAdd(&h[k1 >> 20], 1u);
  __syncthreads();
  unsigned* out = subhist32 + (size_t)g * (NBINS / 2);
  for (int i = tid; i < NBINS / 2; i += 1024)
    out[i] = h[2 * i] | (h[2 * i + 1] << 16);    // counts <= 2048, fit u16
}

// K24: 256 blocks (8 per batch; block (b,q) owns candidate slots
// [E(256q), E(256q+256)), bin-aligned). Each block: rebuild the batch scan
// from the 8 sub-hists (L2-hot), PULL its own candidates from keybuf into
// LDS (bin j belongs to chunk q iff above[j]>>8==q), bitonic-sort the
// chunk (adaptive size), and gather output rows [E1, min(E2,KTOP)).
__global__ __launch_bounds__(512) void select_sort_gather_kernel(const float* __restrict__ in,
                                                                 const unsigned* __restrict__ keybuf,
                                                                 const unsigned short* __restrict__ subhist,
                                                                 float* __restrict__ out) {
  __shared__ unsigned ab_lds[NBINS];             // 16 KiB: slot counters
  __shared__ unsigned long long sb[SCAP + (SCAP >> 5)];   // 8.25 KiB padded
  __shared__ unsigned wtot[8], wsfx[8];
  __shared__ unsigned shE[2];
  __shared__ unsigned sh_D, sh_N;

  const int g = blockIdx.x, tid = threadIdx.x;
  const int b = g >> 3, q = g & 7;
  const int wid = tid >> 6, lane = tid & 63;
  const unsigned x1 = (unsigned)q * CHSLOT, x2 = x1 + CHSLOT;

  if (tid < 2) shE[tid] = 0xffffffffu;

  // ---- Batch scan: totals for my 8 bins [8*tid, 8*tid+8). ----
  unsigned tot[8];
#pragma unroll
  for (int j = 0; j < 8; ++j) tot[j] = 0;
#pragma unroll
  for (int c = 0; c < NCH; ++c) {
    const uint4 v = *(const uint4*)(subhist + (size_t)(b * NCH + c) * NBINS + 8 * tid);
    tot[0] += v.x & 0xffffu; tot[1] += v.x >> 16;
    tot[2] += v.y & 0xffffu; tot[3] += v.y >> 16;
    tot[4] += v.z & 0xffffu; tot[5] += v.z >> 16;
    tot[6] += v.w & 0xffffu; tot[7] += v.w >> 16;
  }
  unsigned s = 0;
#pragma unroll
  for (int j = 0; j < 8; ++j) s += tot[j];

  unsigned p = s;                                // inclusive suffix over lanes
  for (int off = 1; off < 64; off <<= 1) {
    unsigned t = __shfl_down(p, off);
    if (lane + off < 64) p += t;
  }
  if (lane == 0) wtot[wid] = p;
  __syncthreads();
  if (wid == 0) {
    unsigned own = (lane < 8) ? wtot[lane] : 0;
    unsigned p2 = own;
    for (int off = 1; off < 8; off <<= 1) {
      unsigned t = __shfl_down(p2, off);
      if (lane + off < 8) p2 += t;
    }
    if (lane < 8) wsfx[lane] = p2 - own;         // totals of waves above
  }
  __syncthreads();

  unsigned run = wsfx[wid] + (p - s);            // keys strictly above my bins
  unsigned ab[8];
#pragma unroll
  for (int j = 7; j >= 0; --j) {
    ab[j] = run;                                 // above[bin 8*tid+j]
    run += tot[j];
    if (ab[j] < KTOP && run >= KTOP) {           // exactly one bin satisfies
      sh_D = (unsigned)(8 * tid + j);
      sh_N = run;                                // total candidate count
    }
  }

  // ---- Chunk boundaries: E1 = min ab >= x1, E2 = min ab >= x2. ----
  unsigned m1 = 0xffffffffu, m2 = 0xffffffffu;
#pragma unroll
  for (int j = 0; j < 8; ++j) {
    if (ab[j] >= x1 && ab[j] < m1) m1 = ab[j];
    if (ab[j] >= x2 && ab[j] < m2) m2 = ab[j];
  }
  for (int off = 1; off < 64; off <<= 1) {
    unsigned t1 = __shfl_xor(m1, off), t2 = __shfl_xor(m2, off);
    m1 = m1 < t1 ? m1 : t1;
    m2 = m2 < t2 ? m2 : t2;
  }
  if (lane == 0) { atomicMin(&shE[0], m1); atomicMin(&shE[1], m2); }
  __syncthreads();

  const unsigned D = sh_D, N = sh_N;
  const unsigned E1 = shE[0];
  unsigned E2 = (x2 >= N) ? N : shE[1];
  if (E2 > N) E2 = N;
  if (E1 >= KTOP || E1 >= N) return;             // uniform exit: no output here
  unsigned len = E2 - E1;
  if (len == 0) return;
  if (len > SCAP) len = SCAP;                    // safety (degenerate data only)

  // ---- Seed slot counters (ab - E1; foreign bins wrap/overflow -> reject). ----
#pragma unroll
  for (int j = 0; j < 8; ++j) ab_lds[8 * tid + j] = ab[j] - E1;
  for (int i = tid; i < SCAP + (SCAP >> 5); i += 512) sb[i] = 0;
  __syncthreads();

  // ---- Pull candidates: scan the batch's 16K keys (L2-hot). ----
  const unsigned Dfl = D << 20;
  const uint4* kb4 = (const uint4*)(keybuf + (size_t)b * NPB);
  for (int i = tid; i < NPB / 4; i += 512) {
    uint4 kv = kb4[i];
#pragma unroll
    for (int e = 0; e < 4; ++e) {
      unsigned k = (&kv.x)[e];
      if (k >= Dfl) {                            // bin >= D (candidate anywhere)
        unsigned bin = k >> 20;
        if (ab_lds[bin] < len) {                 // racy pre-check (monotonic-safe)
          unsigned slot = atomicAdd(&ab_lds[bin], 1u);
          if (slot < len) {
            unsigned li = (unsigned)(4 * i + e); // row within batch
            sb[PAD(slot)] = ((unsigned long long)k << 32) | (unsigned)~li;
          }
        }
      }
    }
  }
  __syncthreads();

  // ---- Bitonic sort, descending, adaptive size (smallest pow2 >= len). ----
  unsigned S = 256;
  while (S < len) S <<= 1;                       // <= SCAP
  for (unsigned size = 2; size <= S; size <<= 1) {
    for (unsigned stride = size >> 1; stride >= 1; stride >>= 1) {
      if (tid < (int)(S / 2)) {
        int pos = 2 * tid - (tid & (stride - 1));
        bool desc = ((pos & size) == 0);
        unsigned long long a = sb[PAD(pos)], bb = sb[PAD(pos + stride)];
        if (desc ? (a < bb) : (a > bb)) { sb[PAD(pos)] = bb; sb[PAD(pos + stride)] = a; }
      }
      __syncthreads();
    }
  }

  // ---- Gather output rows [E1, gend). ----
  const unsigned gend = (E2 < KTOP) ? E2 : KTOP;
  const int glen = (int)(gend - E1);
  const float4* inb = (const float4*)(in + (size_t)b * NPB * NF);
  float4* outb = (float4*)(out + ((size_t)b * KTOP + E1) * NF);
  for (int u = tid; u < glen * 16; u += 512) {
    int r = u >> 4, f4 = u & 15;
    unsigned long long kv = sb[PAD(r)];
    int gi = (int)(~(unsigned)(kv & 0xffffffffu));
    outb[(size_t)r * 16 + f4] = inb[(size_t)gi * 16 + f4];
  }
}

extern "C" void kernel_launch(void* const* d_in, const int* in_sizes, int n_in,
                              void* d_out, int out_size, void* d_ws, size_t ws_size,
                              hipStream_t stream) {
  const float* in = (const float*)d_in[0];
  float* out = (float*)d_out;

  // d_ws layout: keybuf @0 (2 MiB), subhist u16 @2 MiB (2 MiB).
  unsigned* keybuf    = (unsigned*)d_ws;
  unsigned* subhist32 = (unsigned*)((char*)d_ws + (2u << 20));
  unsigned short* subhist16 = (unsigned short*)subhist32;

  extract_hist_kernel<<<NB * NCH, 1024, 0, stream>>>(in, keybuf, subhist32);
  select_sort_gather_kernel<<<NB * NCH, 512, 0, stream>>>(in, keybuf, subhist16, out);
}